// Round 8
// baseline (186.849 us; speedup 1.0000x reference)
//
#include <hip/hip_runtime.h>

typedef short short8 __attribute__((ext_vector_type(8)));
typedef float f32x4 __attribute__((ext_vector_type(4)));
typedef unsigned int uint4v __attribute__((ext_vector_type(4)));

#define EPS_NUMER_F 1e-8f
#define EPS_D2_F 1e-12f

#define BB 128
#define TT 128
#define DD 1024
#define CHW 3072
#define NC 10
#define MM (BB * TT)
#define NT 48              // CHW / 64 K-tiles

#define GLOAD_LDS16(g, l)                                              \
  __builtin_amdgcn_global_load_lds(                                    \
      (const __attribute__((address_space(1))) void*)(g),              \
      (__attribute__((address_space(3))) void*)(l), 16, 0, 0)

#define DS_READ_B128(dst_, off_) \
  asm volatile("ds_read_b128 %0, %1" : "=v"(dst_) : "v"(off_))
#define DS_WRITE_B128(off_, val_) \
  asm volatile("ds_write_b128 %0, %1" :: "v"(off_), "v"(val_))
#define GLB_LOAD_X4(dst_, voff_, imm_) \
  asm volatile("global_load_dwordx4 %0, %1, %2 offset:" #imm_ \
               : "=v"(dst_) : "v"(voff_), "s"(xbase))
#define SCHED_FENCE() __builtin_amdgcn_sched_barrier(0)

static __device__ __forceinline__ unsigned lds_addr(const void* p) {
  return (unsigned)(unsigned long long)(const __attribute__((address_space(3))) void*)p;
}
static __device__ __forceinline__ unsigned cvt2(float lo, float hi) {
  unsigned r;
  asm("v_cvt_pk_bf16_f32 %0, %1, %2" : "=v"(r) : "v"(lo), "v"(hi));
  return r;
}

static __device__ __forceinline__ short f2bf(float x) {
  unsigned int u = __float_as_uint(x);
  u = (u + 0x7fffu + ((u >> 16) & 1u)) >> 16;
  return (short)u;
}
static __device__ __forceinline__ float bf2f(short x) {
  return __uint_as_float(((unsigned int)(unsigned short)x) << 16);
}

// ---------------------------------------------------------------------------
// W_fe (3072 x 1024 f32, K x N) -> Wt (1024 x 3072 bf16, N x K)
// ---------------------------------------------------------------------------
__global__ __launch_bounds__(256) void k_transpose_w(const float* __restrict__ W,
                                                     short* __restrict__ Wt) {
  __shared__ float tile[32][33];
  const int n0 = blockIdx.x * 32;
  const int k0 = blockIdx.y * 32;
  const int tx = threadIdx.x & 31;
  const int ty = threadIdx.x >> 5;
#pragma unroll
  for (int i = 0; i < 32; i += 8)
    tile[ty + i][tx] = W[(size_t)(k0 + ty + i) * DD + (n0 + tx)];
  __syncthreads();
#pragma unroll
  for (int i = 0; i < 32; i += 8)
    Wt[(size_t)(n0 + ty + i) * CHW + (k0 + tx)] = f2bf(tile[tx][ty + i]);
}

// ---------------------------------------------------------------------------
// Fused 256x256 8-phase GEMM with pipelined LDS reads: F = bf16(X)@Wt^T + b.
// Phase p issues phase p+1's A-quad ds_reads; counted lgkmcnt leaves them in
// flight; q0 issues B(8)+A0+A1. Counted vmcnt ledger: q2 vmcnt(6), q3 vmcnt(4).
// ---------------------------------------------------------------------------
__global__ __launch_bounds__(512, 2) void k_gemm_8ph(const float* __restrict__ X,
                                                     const short* __restrict__ Wt,
                                                     const float* __restrict__ bias,
                                                     short* __restrict__ F) {
  __shared__ short As[2][256 * 64];
  __shared__ short Bs[2][256 * 64];

  const int bid = blockIdx.x;
  const int id = (bid & 7) * 32 + (bid >> 3);
  const int bm = (id >> 2) << 8;
  const int bn = (id & 3) << 8;

  const int tid = threadIdx.x;
  const int lane = tid & 63;
  const int wid = tid >> 6;
  const int wr = wid >> 2;
  const int wc = wid & 3;

  // ---- B staging (gload_lds, pre-swizzled source)
  const int srow = lane >> 3;
  const int sslot = (lane & 7) ^ (lane >> 3);
  const short* bSrc = Wt + (size_t)(bn + srow) * CHW + sslot * 8;

#define STAGE_B_HALF(T_, h_) do {                                            \
    int base_ = (h_) * 128 + wid * 8;                                        \
    GLOAD_LDS16(bSrc + (size_t)(base_) * CHW + (T_) * 64,                    \
                &Bs[(T_) & 1][(base_) * 64]);                                \
    GLOAD_LDS16(bSrc + (size_t)(base_ + 64) * CHW + (T_) * 64,              \
                &Bs[(T_) & 1][(base_ + 64) * 64]);                           \
  } while (0)

  // ---- A staging: asm global loads (vmcnt-only) + cvt_pk + swizzled ds_write
  const int arow_st = wid * 16 + (lane >> 3);
  const unsigned long long xbase = (unsigned long long)X;
  unsigned voff[4];
#pragma unroll
  for (int h = 0; h < 2; ++h)
#pragma unroll
    for (int j = 0; j < 2; ++j)
      voff[h * 2 + j] = (unsigned)(((bm + h * 128 + j * 8 + arow_st) * (size_t)CHW
                                    + (lane & 7) * 8) * 4);
  const unsigned aposb = (unsigned)(((lane & 7) ^ (lane >> 3)) * 16);

  f32x4 ra[4], rb[4];

#define LOAD_A_H0() do {                                                     \
    GLB_LOAD_X4(ra[0], voff[0], 0);  GLB_LOAD_X4(ra[1], voff[0], 16);        \
    GLB_LOAD_X4(ra[2], voff[1], 0);  GLB_LOAD_X4(ra[3], voff[1], 16);        \
  } while (0)
#define LOAD_A_H1() do {                                                     \
    GLB_LOAD_X4(rb[0], voff[2], 0);  GLB_LOAD_X4(rb[1], voff[2], 16);        \
    GLB_LOAD_X4(rb[2], voff[3], 0);  GLB_LOAD_X4(rb[3], voff[3], 16);        \
  } while (0)
#define ADV_A() do { voff[0] += 256; voff[1] += 256; voff[2] += 256; voff[3] += 256; } while (0)
#define WRITE_A_HALF(T_, h_, d_) do {                                        \
    unsigned ad_ = aWrBase + (((T_) & 1) ? 32768u : 0u) + (h_) * 16384u;     \
    uint4v w0_, w1_;                                                         \
    w0_.x = cvt2(d_[0].x, d_[0].y); w0_.y = cvt2(d_[0].z, d_[0].w);          \
    w0_.z = cvt2(d_[1].x, d_[1].y); w0_.w = cvt2(d_[1].z, d_[1].w);          \
    DS_WRITE_B128(ad_, w0_);                                                 \
    w1_.x = cvt2(d_[2].x, d_[2].y); w1_.y = cvt2(d_[2].z, d_[2].w);          \
    w1_.z = cvt2(d_[3].x, d_[3].y); w1_.w = cvt2(d_[3].z, d_[3].w);          \
    DS_WRITE_B128(ad_ + 1024u, w1_);                                         \
  } while (0)

  // fragment read addressing (swizzled)
  const int fr = lane & 15;
  const int sl = lane >> 4;
  const int slotk0 = (0 + sl) ^ (lane & 7);
  const int slotk1 = (4 + sl) ^ (lane & 7);
  const int arow = wr * 128 + fr;
  const int brow = wc * 64 + fr;

  const unsigned aBase0 = lds_addr(&As[0][0]);
  const unsigned bBase0 = lds_addr(&Bs[0][0]);
  const unsigned aWrBase = aBase0 + (unsigned)(arow_st * 128) + aposb;

  short8 bf_[8];        // B frags for current tile (read at q0)
  short8 aqE[4], aqO[4];// A-quad ping-pong: E = quads 0,2; O = quads 1,3
  f32x4 acc[8][4] = {};

#define READ_B8(bb_) do {                                                    \
    _Pragma("unroll")                                                        \
    for (int ni = 0; ni < 4; ++ni) {                                         \
      DS_READ_B128(bf_[ni * 2 + 0], (bb_) + (unsigned)((brow + ni * 16) * 128 + slotk0 * 16)); \
      DS_READ_B128(bf_[ni * 2 + 1], (bb_) + (unsigned)((brow + ni * 16) * 128 + slotk1 * 16)); \
    }                                                                        \
  } while (0)
#define READ_AQ(set_, q_, ab_) do {                                          \
    DS_READ_B128(set_[0], (ab_) + (unsigned)((arow + (2*(q_))    *16)*128 + slotk0*16)); \
    DS_READ_B128(set_[1], (ab_) + (unsigned)((arow + (2*(q_))    *16)*128 + slotk1*16)); \
    DS_READ_B128(set_[2], (ab_) + (unsigned)((arow + (2*(q_) + 1)*16)*128 + slotk0*16)); \
    DS_READ_B128(set_[3], (ab_) + (unsigned)((arow + (2*(q_) + 1)*16)*128 + slotk1*16)); \
  } while (0)
#define MFMA16(q_, set_) do {                                                \
    _Pragma("unroll")                                                        \
    for (int m2 = 0; m2 < 2; ++m2)                                           \
      _Pragma("unroll")                                                      \
      for (int ks = 0; ks < 2; ++ks)                                         \
        _Pragma("unroll")                                                    \
        for (int ni = 0; ni < 4; ++ni)                                       \
          acc[2*(q_)+m2][ni] = __builtin_amdgcn_mfma_f32_16x16x32_bf16(      \
              set_[m2*2+ks], bf_[ni*2+ks], acc[2*(q_)+m2][ni], 0, 0, 0);     \
  } while (0)

  // ---- prologue: A(0) + B(0) + B(1); vmcnt(4) drains A+B(0); write A(0)
  LOAD_A_H0();
  LOAD_A_H1();
  ADV_A();
  STAGE_B_HALF(0, 0); STAGE_B_HALF(0, 1);
  STAGE_B_HALF(1, 0); STAGE_B_HALF(1, 1);
  SCHED_FENCE();
  asm volatile("s_waitcnt vmcnt(4)");
  SCHED_FENCE();
  WRITE_A_HALF(0, 0, ra);
  WRITE_A_HALF(0, 1, rb);
  asm volatile("s_waitcnt lgkmcnt(0)");
  SCHED_FENCE();
  __builtin_amdgcn_s_barrier();

  for (int T = 0; T < NT; ++T) {
    const unsigned ab = aBase0 + ((T & 1) ? 32768u : 0u);
    const unsigned bb = bBase0 + ((T & 1) ? 32768u : 0u);

    // ---- q0: read B(8)+A0+A1 (16); issue A(T+1)h0 globals.
    // lgkm(4) leaves A1 in flight; MFMA(0) needs B+A0.
    READ_B8(bb);
    READ_AQ(aqE, 0, ab);
    READ_AQ(aqO, 1, ab);
    if (T + 1 < NT) LOAD_A_H0();
    SCHED_FENCE();
    __builtin_amdgcn_s_barrier();
    asm volatile("s_waitcnt lgkmcnt(4)");
    SCHED_FENCE();
    __builtin_amdgcn_s_setprio(1);
    MFMA16(0, aqE);
    __builtin_amdgcn_s_setprio(0);
    SCHED_FENCE();
    __builtin_amdgcn_s_barrier();

    // ---- q1: read A2 (next); issue A(T+1)h1 globals. lgkm(4) leaves A2.
    READ_AQ(aqE, 2, ab);
    if (T + 1 < NT) LOAD_A_H1();
    ADV_A();
    SCHED_FENCE();
    __builtin_amdgcn_s_barrier();
    asm volatile("s_waitcnt lgkmcnt(4)");
    SCHED_FENCE();
    __builtin_amdgcn_s_setprio(1);
    MFMA16(1, aqO);
    __builtin_amdgcn_s_setprio(0);
    SCHED_FENCE();
    __builtin_amdgcn_s_barrier();

    // ---- q2: stage B(T+2)h0; vmcnt(6) drains B(T+1)+A(T+1)h0; write A h0;
    // read A3 (next). lgkm(4) drains A2 + h0 writes (cross-wave safe), leaves A3.
    if (T + 2 < NT) {
      STAGE_B_HALF(T + 2, 0);
      SCHED_FENCE();
      asm volatile("s_waitcnt vmcnt(6)");
      SCHED_FENCE();
    } else if (T + 1 < NT) {
      SCHED_FENCE();
      asm volatile("s_waitcnt vmcnt(4)");
      SCHED_FENCE();
    }
    if (T + 1 < NT) WRITE_A_HALF(T + 1, 0, ra);
    READ_AQ(aqO, 3, ab);
    SCHED_FENCE();
    __builtin_amdgcn_s_barrier();
    asm volatile("s_waitcnt lgkmcnt(4)");
    SCHED_FENCE();
    __builtin_amdgcn_s_setprio(1);
    MFMA16(2, aqE);
    __builtin_amdgcn_s_setprio(0);
    SCHED_FENCE();
    __builtin_amdgcn_s_barrier();

    // ---- q3: stage B(T+2)h1; vmcnt(4) drains A(T+1)h1; write A h1.
    // lgkm(2) drains A3 (leaves h1 writes); post-MFMA lgkm(0) drains writes.
    if (T + 2 < NT) {
      STAGE_B_HALF(T + 2, 1);
      SCHED_FENCE();
      asm volatile("s_waitcnt vmcnt(4)");
      SCHED_FENCE();
    } else if (T + 1 < NT) {
      SCHED_FENCE();
      asm volatile("s_waitcnt vmcnt(0)");
      SCHED_FENCE();
    }
    if (T + 1 < NT) WRITE_A_HALF(T + 1, 1, rb);
    SCHED_FENCE();
    __builtin_amdgcn_s_barrier();
    if (T + 1 < NT) {
      asm volatile("s_waitcnt lgkmcnt(2)");
    } else {
      asm volatile("s_waitcnt lgkmcnt(0)");
    }
    SCHED_FENCE();
    __builtin_amdgcn_s_setprio(1);
    MFMA16(3, aqO);
    __builtin_amdgcn_s_setprio(0);
    asm volatile("s_waitcnt lgkmcnt(0)");
    SCHED_FENCE();
    __builtin_amdgcn_s_barrier();
  }

  // epilogue: C/D layout col = lane&15, row = (lane>>4)*4 + q
  const int cc = lane & 15;
  const int crr = sl << 2;
#pragma unroll
  for (int ni = 0; ni < 4; ++ni) {
    int col = bn + wc * 64 + ni * 16 + cc;
    float bv = bias[col];
#pragma unroll
    for (int mi = 0; mi < 8; ++mi) {
      int row0 = bm + wr * 128 + mi * 16 + crr;
#pragma unroll
      for (int q = 0; q < 4; ++q)
        F[(size_t)(row0 + q) * DD + col] = f2bf(acc[mi][ni][q] + bv);
    }
  }
#undef READ_B8
#undef READ_AQ
#undef MFMA16
#undef STAGE_B_HALF
}

// ---------------------------------------------------------------------------
// Kernel 3: per (batch, t-half): Gram via MFMA -> d2 -> sims -> causal numer
// -> pow/normalize -> out.
// ---------------------------------------------------------------------------
__global__ __launch_bounds__(256) void k_batch_sims(const short* __restrict__ F,
                                                    const float* __restrict__ teach,
                                                    const float* __restrict__ cptr,
                                                    const float* __restrict__ gptr,
                                                    float* __restrict__ out) {
  __shared__ short ftile[128][40];
  __shared__ float simsT[64][129];
  __shared__ float sqv[128];
  __shared__ float sqp[256];
  __shared__ float teach_s[128][NC];
  __shared__ float numer[64][NC];
  __shared__ float rsum[64];

  const int b = blockIdx.x >> 1;
  const int half = blockIdx.x & 1;
  const int tid = threadIdx.x;
  const int lane = tid & 63;
  const int w = tid >> 6;
  const size_t fbase = (size_t)b * TT * DD;

  for (int idx = tid; idx < TT * NC; idx += 256)
    teach_s[idx / NC][idx % NC] = teach[(size_t)b * TT * NC + idx];

  {
    int row = tid >> 1;
    int kh = (tid & 1) << 9;
    const short* fp = F + fbase + (size_t)row * DD + kh;
    float s = 0.f;
    for (int k = 0; k < 512; k += 8) {
      short8 v = *reinterpret_cast<const short8*>(fp + k);
#pragma unroll
      for (int j = 0; j < 8; ++j) { float x = bf2f(v[j]); s += x * x; }
    }
    sqp[tid] = s;
  }
  __syncthreads();
  if (tid < 128) sqv[tid] = sqp[2 * tid] + sqp[2 * tid + 1];
  __syncthreads();

  f32x4 acc[2][4] = {};
  const int fr = lane & 15;
  const int fk = (lane >> 4) << 3;
  for (int k0 = 0; k0 < DD; k0 += 32) {
#pragma unroll
    for (int i = 0; i < 2; ++i) {
      int idx = tid + (i << 8);
      int row = idx >> 2;
      int kc = (idx & 3) << 3;
      short8 v = *reinterpret_cast<const short8*>(F + fbase + (size_t)row * DD + (k0 + kc));
      *reinterpret_cast<short8*>(&ftile[row][kc]) = v;
    }
    __syncthreads();
    short8 af[2], bfv[4];
#pragma unroll
    for (int mi = 0; mi < 2; ++mi)
      af[mi] = *reinterpret_cast<const short8*>(&ftile[w * 32 + mi * 16 + fr][fk]);
#pragma unroll
    for (int ni = 0; ni < 4; ++ni)
      bfv[ni] = *reinterpret_cast<const short8*>(&ftile[half * 64 + ni * 16 + fr][fk]);
#pragma unroll
    for (int mi = 0; mi < 2; ++mi)
#pragma unroll
      for (int ni = 0; ni < 4; ++ni)
        acc[mi][ni] = __builtin_amdgcn_mfma_f32_16x16x32_bf16(af[mi], bfv[ni], acc[mi][ni], 0, 0, 0);
    __syncthreads();
  }

  const float c0 = cptr[0];
  const int cc = lane & 15;
  const int crr = (lane >> 4) << 2;
#pragma unroll
  for (int mi = 0; mi < 2; ++mi) {
#pragma unroll
    for (int ni = 0; ni < 4; ++ni) {
#pragma unroll
      for (int q = 0; q < 4; ++q) {
        int s_g = w * 32 + mi * 16 + crr + q;
        int tl = ni * 16 + cc;
        int t_g = half * 64 + tl;
        float g = acc[mi][ni][q];
        float d2 = sqv[s_g] + sqv[t_g] - 2.0f * g;
        d2 = fmaxf(d2, EPS_D2_F);
        float dist = sqrtf(sqrtf(d2));
        simsT[tl][s_g] = (s_g < t_g) ? expf(-c0 * dist) : 0.0f;
      }
    }
  }
  __syncthreads();

  const float gam = gptr[0];
  for (int idx = tid; idx < 64 * NC; idx += 256) {
    int tl = idx / NC, c = idx % NC;
    float s = 0.f;
#pragma unroll 4
    for (int si = 0; si < TT; ++si)
      s += simsT[tl][si] * teach_s[si][c];
    float v = EPS_NUMER_F + s;
    numer[tl][c] = (gam == 1.0f) ? v : powf(v, gam);
  }
  __syncthreads();
  if (tid < 64) {
    float s = 0.f;
#pragma unroll
    for (int c = 0; c < NC; ++c) s += numer[tid][c];
    rsum[tid] = s;
  }
  __syncthreads();
  for (int idx = tid; idx < 64 * NC; idx += 256) {
    int tl = idx / NC, c = idx % NC;
    int t_g = half * 64 + tl;
    float v = numer[tl][c] / rsum[tl];
    if (t_g == 0) v = EPS_NUMER_F;
    out[(size_t)b * TT * NC + (size_t)t_g * NC + c] = v;
  }
}

// ---------------------------------------------------------------------------
extern "C" void kernel_launch(void* const* d_in, const int* in_sizes, int n_in,
                              void* d_out, int out_size, void* d_ws, size_t ws_size,
                              hipStream_t stream) {
  const float* data = (const float*)d_in[1];
  const float* teach = (const float*)d_in[2];
  const float* Wfe = (const float*)d_in[3];
  const float* bfe = (const float*)d_in[4];
  const float* cp = (const float*)d_in[5];
  const float* gp = (const float*)d_in[6];
  float* outp = (float*)d_out;

  char* ws = (char*)d_ws;
  short* Wt = (short*)ws;                             // @0:   6.29 MB
  short* F = (short*)(ws + (size_t)8 * 1024 * 1024);  // @8MB: 33.55 MB

  k_transpose_w<<<dim3(DD / 32, CHW / 32), 256, 0, stream>>>(Wfe, Wt);
  k_gemm_8ph<<<dim3((MM / 256) * (DD / 256)), 512, 0, stream>>>(data, Wt, bfe, F);
  k_batch_sims<<<dim3(BB * 2), 256, 0, stream>>>(F, teach, cp, gp, outp);
}

// Round 9
// 150.450 us; speedup vs baseline: 1.2419x; 1.2419x over previous
//
#include <hip/hip_runtime.h>

typedef short short8 __attribute__((ext_vector_type(8)));
typedef float f32x4 __attribute__((ext_vector_type(4)));
typedef unsigned int uint4v __attribute__((ext_vector_type(4)));

#define EPS_NUMER_F 1e-8f
#define EPS_D2_F 1e-12f

#define BB 128
#define TT 128
#define DD 1024
#define CHW 3072
#define NC 10
#define MM (BB * TT)
#define NT 48              // CHW / 64 K-tiles

#define GLOAD_LDS16(g, l)                                              \
  __builtin_amdgcn_global_load_lds(                                    \
      (const __attribute__((address_space(1))) void*)(g),              \
      (__attribute__((address_space(3))) void*)(l), 16, 0, 0)

#define DS_READ_B128(dst_, off_) \
  asm volatile("ds_read_b128 %0, %1" : "=v"(dst_) : "v"(off_))
#define DS_WRITE_B128(off_, val_) \
  asm volatile("ds_write_b128 %0, %1" :: "v"(off_), "v"(val_))
#define GLB_LOAD_X4(dst_, voff_, imm_) \
  asm volatile("global_load_dwordx4 %0, %1, %2 offset:" #imm_ \
               : "=v"(dst_) : "v"(voff_), "s"(xbase))
#define SCHED_FENCE() __builtin_amdgcn_sched_barrier(0)

static __device__ __forceinline__ unsigned lds_addr(const void* p) {
  return (unsigned)(unsigned long long)(const __attribute__((address_space(3))) void*)p;
}
static __device__ __forceinline__ unsigned cvt2(float lo, float hi) {
  unsigned r;
  asm("v_cvt_pk_bf16_f32 %0, %1, %2" : "=v"(r) : "v"(lo), "v"(hi));
  return r;
}

static __device__ __forceinline__ short f2bf(float x) {
  unsigned int u = __float_as_uint(x);
  u = (u + 0x7fffu + ((u >> 16) & 1u)) >> 16;
  return (short)u;
}
static __device__ __forceinline__ float bf2f(short x) {
  return __uint_as_float(((unsigned int)(unsigned short)x) << 16);
}

// ---------------------------------------------------------------------------
// W_fe (3072 x 1024 f32, K x N) -> Wt (1024 x 3072 bf16, N x K)
// ---------------------------------------------------------------------------
__global__ __launch_bounds__(256) void k_transpose_w(const float* __restrict__ W,
                                                     short* __restrict__ Wt) {
  __shared__ float tile[32][33];
  const int n0 = blockIdx.x * 32;
  const int k0 = blockIdx.y * 32;
  const int tx = threadIdx.x & 31;
  const int ty = threadIdx.x >> 5;
#pragma unroll
  for (int i = 0; i < 32; i += 8)
    tile[ty + i][tx] = W[(size_t)(k0 + ty + i) * DD + (n0 + tx)];
  __syncthreads();
#pragma unroll
  for (int i = 0; i < 32; i += 8)
    Wt[(size_t)(n0 + ty + i) * CHW + (k0 + tx)] = f2bf(tile[tx][ty + i]);
}

// ---------------------------------------------------------------------------
// Fused 256x256 8-phase GEMM (round-7 base): F = bf16(X) @ Wt^T + b.
// Change vs r7: A globals issued at q2/q3 for tile T+2 (4-phase latency slack,
// time-sharing ra/rb after the ds_writes consume them); uniform vmcnt(8).
// Steady per-wave VMEM queue = 12: [Bh0 2, Ah0 4, Bh1 2, Ah1 4].
// ---------------------------------------------------------------------------
__global__ __launch_bounds__(512, 2) void k_gemm_8ph(const float* __restrict__ X,
                                                     const short* __restrict__ Wt,
                                                     const float* __restrict__ bias,
                                                     short* __restrict__ F) {
  __shared__ short As[2][256 * 64];
  __shared__ short Bs[2][256 * 64];

  const int bid = blockIdx.x;
  const int id = (bid & 7) * 32 + (bid >> 3);
  const int bm = (id >> 2) << 8;
  const int bn = (id & 3) << 8;

  const int tid = threadIdx.x;
  const int lane = tid & 63;
  const int wid = tid >> 6;
  const int wr = wid >> 2;
  const int wc = wid & 3;

  // ---- B staging (gload_lds, pre-swizzled source)
  const int srow = lane >> 3;
  const int sslot = (lane & 7) ^ (lane >> 3);
  const short* bSrc = Wt + (size_t)(bn + srow) * CHW + sslot * 8;

#define STAGE_B_HALF(T_, h_) do {                                            \
    int base_ = (h_) * 128 + wid * 8;                                        \
    GLOAD_LDS16(bSrc + (size_t)(base_) * CHW + (T_) * 64,                    \
                &Bs[(T_) & 1][(base_) * 64]);                                \
    GLOAD_LDS16(bSrc + (size_t)(base_ + 64) * CHW + (T_) * 64,              \
                &Bs[(T_) & 1][(base_ + 64) * 64]);                           \
  } while (0)

  // ---- A staging: asm global loads (vmcnt-only) + cvt_pk + swizzled ds_write
  const int arow_st = wid * 16 + (lane >> 3);
  const unsigned long long xbase = (unsigned long long)X;
  unsigned voff[4];
#pragma unroll
  for (int h = 0; h < 2; ++h)
#pragma unroll
    for (int j = 0; j < 2; ++j)
      voff[h * 2 + j] = (unsigned)(((bm + h * 128 + j * 8 + arow_st) * (size_t)CHW
                                    + (lane & 7) * 8) * 4);
  const unsigned aposb = (unsigned)(((lane & 7) ^ (lane >> 3)) * 16);

  f32x4 ra[4], rb[4];

#define LOAD_A_H0() do {                                                     \
    GLB_LOAD_X4(ra[0], voff[0], 0);  GLB_LOAD_X4(ra[1], voff[0], 16);        \
    GLB_LOAD_X4(ra[2], voff[1], 0);  GLB_LOAD_X4(ra[3], voff[1], 16);        \
  } while (0)
#define LOAD_A_H1() do {                                                     \
    GLB_LOAD_X4(rb[0], voff[2], 0);  GLB_LOAD_X4(rb[1], voff[2], 16);        \
    GLB_LOAD_X4(rb[2], voff[3], 0);  GLB_LOAD_X4(rb[3], voff[3], 16);        \
  } while (0)
#define ADV_A() do { voff[0] += 256; voff[1] += 256; voff[2] += 256; voff[3] += 256; } while (0)
#define WRITE_A_HALF(T_, h_, d_) do {                                        \
    unsigned ad_ = aWrBase + (((T_) & 1) ? 32768u : 0u) + (h_) * 16384u;     \
    uint4v w0_, w1_;                                                         \
    w0_.x = cvt2(d_[0].x, d_[0].y); w0_.y = cvt2(d_[0].z, d_[0].w);          \
    w0_.z = cvt2(d_[1].x, d_[1].y); w0_.w = cvt2(d_[1].z, d_[1].w);          \
    DS_WRITE_B128(ad_, w0_);                                                 \
    w1_.x = cvt2(d_[2].x, d_[2].y); w1_.y = cvt2(d_[2].z, d_[2].w);          \
    w1_.z = cvt2(d_[3].x, d_[3].y); w1_.w = cvt2(d_[3].z, d_[3].w);          \
    DS_WRITE_B128(ad_ + 1024u, w1_);                                         \
  } while (0)

  // fragment read addressing (swizzled)
  const int fr = lane & 15;
  const int sl = lane >> 4;
  const int slotk0 = (0 + sl) ^ (lane & 7);
  const int slotk1 = (4 + sl) ^ (lane & 7);
  const int arow = wr * 128 + fr;
  const int brow = wc * 64 + fr;

  const unsigned aBase0 = lds_addr(&As[0][0]);
  const unsigned bBase0 = lds_addr(&Bs[0][0]);
  const unsigned aWrBase = aBase0 + (unsigned)(arow_st * 128) + aposb;

  short8 bf_[8];
  short8 aq[4];
  f32x4 acc[8][4] = {};

#define READ_B8(bb_) do {                                                    \
    _Pragma("unroll")                                                        \
    for (int ni = 0; ni < 4; ++ni) {                                         \
      DS_READ_B128(bf_[ni * 2 + 0], (bb_) + (unsigned)((brow + ni * 16) * 128 + slotk0 * 16)); \
      DS_READ_B128(bf_[ni * 2 + 1], (bb_) + (unsigned)((brow + ni * 16) * 128 + slotk1 * 16)); \
    }                                                                        \
  } while (0)
#define READ_AQ(q_, ab_) do {                                                \
    DS_READ_B128(aq[0], (ab_) + (unsigned)((arow + (2*(q_))    *16)*128 + slotk0*16)); \
    DS_READ_B128(aq[1], (ab_) + (unsigned)((arow + (2*(q_))    *16)*128 + slotk1*16)); \
    DS_READ_B128(aq[2], (ab_) + (unsigned)((arow + (2*(q_) + 1)*16)*128 + slotk0*16)); \
    DS_READ_B128(aq[3], (ab_) + (unsigned)((arow + (2*(q_) + 1)*16)*128 + slotk1*16)); \
  } while (0)
#define MFMA16(q_) do {                                                      \
    _Pragma("unroll")                                                        \
    for (int m2 = 0; m2 < 2; ++m2)                                           \
      _Pragma("unroll")                                                      \
      for (int ks = 0; ks < 2; ++ks)                                         \
        _Pragma("unroll")                                                    \
        for (int ni = 0; ni < 4; ++ni)                                       \
          acc[2*(q_)+m2][ni] = __builtin_amdgcn_mfma_f32_16x16x32_bf16(      \
              aq[m2*2+ks], bf_[ni*2+ks], acc[2*(q_)+m2][ni], 0, 0, 0);       \
  } while (0)

  // ---- prologue: put the VMEM queue in steady shape.
  // queue after: [B(1)h0 2, A(1)h0 4, B(1)h1 2, A(1)h1 4] = 12; LDS has tile 0.
  LOAD_A_H0();                       // A(0): 8
  LOAD_A_H1();
  STAGE_B_HALF(0, 0); STAGE_B_HALF(0, 1);  // B(0): 4
  SCHED_FENCE();
  asm volatile("s_waitcnt vmcnt(4)");      // drain A(0), leave B(0)
  SCHED_FENCE();
  WRITE_A_HALF(0, 0, ra);
  WRITE_A_HALF(0, 1, rb);
  ADV_A();                                 // voff -> tile 1
  STAGE_B_HALF(1, 0);
  LOAD_A_H0();                             // A(1)h0
  STAGE_B_HALF(1, 1);
  LOAD_A_H1();                             // A(1)h1
  ADV_A();                                 // voff -> tile 2
  SCHED_FENCE();
  asm volatile("s_waitcnt vmcnt(12)");     // drain B(0)
  SCHED_FENCE();
  asm volatile("s_waitcnt lgkmcnt(0)");    // A(0) writes done
  SCHED_FENCE();
  __builtin_amdgcn_s_barrier();

  for (int T = 0; T < NT; ++T) {
    const unsigned ab = aBase0 + ((T & 1) ? 32768u : 0u);
    const unsigned bb = bBase0 + ((T & 1) ? 32768u : 0u);

    // ---- q0: read B(8)+A quad 0; no VMEM.
    READ_B8(bb);
    READ_AQ(0, ab);
    SCHED_FENCE();
    __builtin_amdgcn_s_barrier();
    asm volatile("s_waitcnt lgkmcnt(0)");
    SCHED_FENCE();
    __builtin_amdgcn_s_setprio(1);
    MFMA16(0);
    __builtin_amdgcn_s_setprio(0);
    SCHED_FENCE();
    __builtin_amdgcn_s_barrier();

    // ---- q1: A quad 1; no VMEM.
    READ_AQ(1, ab);
    SCHED_FENCE();
    __builtin_amdgcn_s_barrier();
    asm volatile("s_waitcnt lgkmcnt(0)");
    SCHED_FENCE();
    __builtin_amdgcn_s_setprio(1);
    MFMA16(1);
    __builtin_amdgcn_s_setprio(0);
    SCHED_FENCE();
    __builtin_amdgcn_s_barrier();

    // ---- q2: A quad 2; stage B(T+2)h0; vmcnt(8) drains B(T+1)h0+A(T+1)h0;
    // write A(T+1)h0; issue A(T+2)h0 (ra free after cvts — in-order issue).
    READ_AQ(2, ab);
    if (T + 2 < NT) {
      STAGE_B_HALF(T + 2, 0);
      SCHED_FENCE();
      asm volatile("s_waitcnt vmcnt(8)");
      SCHED_FENCE();
    } else if (T + 1 < NT) {
      SCHED_FENCE();
      asm volatile("s_waitcnt vmcnt(6)");
      SCHED_FENCE();
    }
    if (T + 1 < NT) WRITE_A_HALF(T + 1, 0, ra);
    if (T + 2 < NT) LOAD_A_H0();
    SCHED_FENCE();
    __builtin_amdgcn_s_barrier();
    if (T + 1 < NT) {
      asm volatile("s_waitcnt lgkmcnt(2)");   // drain reads, leave 2 writes
    } else {
      asm volatile("s_waitcnt lgkmcnt(0)");
    }
    SCHED_FENCE();
    __builtin_amdgcn_s_setprio(1);
    MFMA16(2);
    __builtin_amdgcn_s_setprio(0);
    SCHED_FENCE();
    __builtin_amdgcn_s_barrier();

    // ---- q3: A quad 3; stage B(T+2)h1; vmcnt(8) drains B(T+1)h1+A(T+1)h1;
    // write A(T+1)h1; issue A(T+2)h1; final lgkm(0) drains writes pre-barrier.
    READ_AQ(3, ab);
    if (T + 2 < NT) {
      STAGE_B_HALF(T + 2, 1);
      SCHED_FENCE();
      asm volatile("s_waitcnt vmcnt(8)");
      SCHED_FENCE();
    } else if (T + 1 < NT) {
      SCHED_FENCE();
      asm volatile("s_waitcnt vmcnt(0)");
      SCHED_FENCE();
    }
    if (T + 1 < NT) WRITE_A_HALF(T + 1, 1, rb);
    if (T + 2 < NT) {
      LOAD_A_H1();
      ADV_A();
    }
    SCHED_FENCE();
    __builtin_amdgcn_s_barrier();
    if (T + 1 < NT) {
      asm volatile("s_waitcnt lgkmcnt(2)");
    } else {
      asm volatile("s_waitcnt lgkmcnt(0)");
    }
    SCHED_FENCE();
    __builtin_amdgcn_s_setprio(1);
    MFMA16(3);
    __builtin_amdgcn_s_setprio(0);
    asm volatile("s_waitcnt lgkmcnt(0)");
    SCHED_FENCE();
    __builtin_amdgcn_s_barrier();
  }

  // epilogue: C/D layout col = lane&15, row = (lane>>4)*4 + q
  const int cc = lane & 15;
  const int crr = sl << 2;
#pragma unroll
  for (int ni = 0; ni < 4; ++ni) {
    int col = bn + wc * 64 + ni * 16 + cc;
    float bv = bias[col];
#pragma unroll
    for (int mi = 0; mi < 8; ++mi) {
      int row0 = bm + wr * 128 + mi * 16 + crr;
#pragma unroll
      for (int q = 0; q < 4; ++q)
        F[(size_t)(row0 + q) * DD + col] = f2bf(acc[mi][ni][q] + bv);
    }
  }
#undef READ_B8
#undef READ_AQ
#undef MFMA16
#undef STAGE_B_HALF
}

// ---------------------------------------------------------------------------
// Kernel 3: per (batch, t-half): Gram via MFMA -> d2 -> sims -> causal numer
// -> pow/normalize -> out.
// ---------------------------------------------------------------------------
__global__ __launch_bounds__(256) void k_batch_sims(const short* __restrict__ F,
                                                    const float* __restrict__ teach,
                                                    const float* __restrict__ cptr,
                                                    const float* __restrict__ gptr,
                                                    float* __restrict__ out) {
  __shared__ short ftile[128][40];
  __shared__ float simsT[64][129];
  __shared__ float sqv[128];
  __shared__ float sqp[256];
  __shared__ float teach_s[128][NC];
  __shared__ float numer[64][NC];
  __shared__ float rsum[64];

  const int b = blockIdx.x >> 1;
  const int half = blockIdx.x & 1;
  const int tid = threadIdx.x;
  const int lane = tid & 63;
  const int w = tid >> 6;
  const size_t fbase = (size_t)b * TT * DD;

  for (int idx = tid; idx < TT * NC; idx += 256)
    teach_s[idx / NC][idx % NC] = teach[(size_t)b * TT * NC + idx];

  {
    int row = tid >> 1;
    int kh = (tid & 1) << 9;
    const short* fp = F + fbase + (size_t)row * DD + kh;
    float s = 0.f;
    for (int k = 0; k < 512; k += 8) {
      short8 v = *reinterpret_cast<const short8*>(fp + k);
#pragma unroll
      for (int j = 0; j < 8; ++j) { float x = bf2f(v[j]); s += x * x; }
    }
    sqp[tid] = s;
  }
  __syncthreads();
  if (tid < 128) sqv[tid] = sqp[2 * tid] + sqp[2 * tid + 1];
  __syncthreads();

  f32x4 acc[2][4] = {};
  const int fr = lane & 15;
  const int fk = (lane >> 4) << 3;
  for (int k0 = 0; k0 < DD; k0 += 32) {
#pragma unroll
    for (int i = 0; i < 2; ++i) {
      int idx = tid + (i << 8);
      int row = idx >> 2;
      int kc = (idx & 3) << 3;
      short8 v = *reinterpret_cast<const short8*>(F + fbase + (size_t)row * DD + (k0 + kc));
      *reinterpret_cast<short8*>(&ftile[row][kc]) = v;
    }
    __syncthreads();
    short8 af[2], bfv[4];
#pragma unroll
    for (int mi = 0; mi < 2; ++mi)
      af[mi] = *reinterpret_cast<const short8*>(&ftile[w * 32 + mi * 16 + fr][fk]);
#pragma unroll
    for (int ni = 0; ni < 4; ++ni)
      bfv[ni] = *reinterpret_cast<const short8*>(&ftile[half * 64 + ni * 16 + fr][fk]);
#pragma unroll
    for (int mi = 0; mi < 2; ++mi)
#pragma unroll
      for (int ni = 0; ni < 4; ++ni)
        acc[mi][ni] = __builtin_amdgcn_mfma_f32_16x16x32_bf16(af[mi], bfv[ni], acc[mi][ni], 0, 0, 0);
    __syncthreads();
  }

  const float c0 = cptr[0];
  const int cc = lane & 15;
  const int crr = (lane >> 4) << 2;
#pragma unroll
  for (int mi = 0; mi < 2; ++mi) {
#pragma unroll
    for (int ni = 0; ni < 4; ++ni) {
#pragma unroll
      for (int q = 0; q < 4; ++q) {
        int s_g = w * 32 + mi * 16 + crr + q;
        int tl = ni * 16 + cc;
        int t_g = half * 64 + tl;
        float g = acc[mi][ni][q];
        float d2 = sqv[s_g] + sqv[t_g] - 2.0f * g;
        d2 = fmaxf(d2, EPS_D2_F);
        float dist = sqrtf(sqrtf(d2));
        simsT[tl][s_g] = (s_g < t_g) ? expf(-c0 * dist) : 0.0f;
      }
    }
  }
  __syncthreads();

  const float gam = gptr[0];
  for (int idx = tid; idx < 64 * NC; idx += 256) {
    int tl = idx / NC, c = idx % NC;
    float s = 0.f;
#pragma unroll 4
    for (int si = 0; si < TT; ++si)
      s += simsT[tl][si] * teach_s[si][c];
    float v = EPS_NUMER_F + s;
    numer[tl][c] = (gam == 1.0f) ? v : powf(v, gam);
  }
  __syncthreads();
  if (tid < 64) {
    float s = 0.f;
#pragma unroll
    for (int c = 0; c < NC; ++c) s += numer[tid][c];
    rsum[tid] = s;
  }
  __syncthreads();
  for (int idx = tid; idx < 64 * NC; idx += 256) {
    int tl = idx / NC, c = idx % NC;
    int t_g = half * 64 + tl;
    float v = numer[tl][c] / rsum[tl];
    if (t_g == 0) v = EPS_NUMER_F;
    out[(size_t)b * TT * NC + (size_t)t_g * NC + c] = v;
  }
}

// ---------------------------------------------------------------------------
extern "C" void kernel_launch(void* const* d_in, const int* in_sizes, int n_in,
                              void* d_out, int out_size, void* d_ws, size_t ws_size,
                              hipStream_t stream) {
  const float* data = (const float*)d_in[1];
  const float* teach = (const float*)d_in[2];
  const float* Wfe = (const float*)d_in[3];
  const float* bfe = (const float*)d_in[4];
  const float* cp = (const float*)d_in[5];
  const float* gp = (const float*)d_in[6];
  float* outp = (float*)d_out;

  char* ws = (char*)d_ws;
  short* Wt = (short*)ws;                             // @0:   6.29 MB
  short* F = (short*)(ws + (size_t)8 * 1024 * 1024);  // @8MB: 33.55 MB

  k_transpose_w<<<dim3(DD / 32, CHW / 32), 256, 0, stream>>>(Wfe, Wt);
  k_gemm_8ph<<<dim3((MM / 256) * (DD / 256)), 512, 0, stream>>>(data, Wt, bfe, F);
  k_batch_sims<<<dim3(BB * 2), 256, 0, stream>>>(F, teach, cp, gp, outp);
}